// Round 9
// baseline (432.525 us; speedup 1.0000x reference)
//
#include <hip/hip_runtime.h>
#include <hip/hip_bf16.h>
#include <cmath>
#include <math.h>

namespace {

constexpr int Bn = 4;
constexpr int Cn = 64;
constexpr int Wn = 64;
constexpr int Hn = 1024;
constexpr int HWn = Wn * Hn;      // 65536
constexpr int CHWn = Cn * HWn;    // 4194304

typedef float f32x4 __attribute__((ext_vector_type(4)));
typedef short bf16x8 __attribute__((ext_vector_type(8)));
union Frag { uint4 u; bf16x8 s; };

// Compile-time shift trig (index 0..2 = shift -1..+1).
constexpr float kCA[3] = {0.9999811753f, 1.0f, 0.9999811753f};   // cos(sw*AZI)
constexpr float kSA[3] = {-0.0061358846f, 0.0f, 0.0061358846f};  // sin(sw*AZI)
constexpr float kCI[3] = {0.9999658257f, 1.0f, 0.9999658257f};   // cos(sh*INC)
constexpr float kSI[3] = {-0.0082672549f, 0.0f, 0.0082672549f};  // sin(sh*INC)

// RNE pack of two f32 -> packed bf16x2 (compiler emits v_cvt_pk_bf16_f32).
__device__ inline unsigned packbf(float a, float b) {
  union { __hip_bfloat162 h; unsigned u; } c;
  c.h = __float22bfloat162_rn(make_float2(a, b));
  return c.u;
}
__device__ inline float bflo(unsigned d) { return __uint_as_float(d << 16); }
__device__ inline float bfhi(unsigned d) { return __uint_as_float(d & 0xFFFF0000u); }

// Async global->LDS, 16B per lane. lptr must be wave-uniform; HW writes
// lptr + lane*16 for each active lane.
__device__ inline void gload16(const void* g, void* l) {
  __builtin_amdgcn_global_load_lds(
      (const __attribute__((address_space(1))) void*)g,
      (__attribute__((address_space(3))) void*)l, 16, 0, 0);
}

// ---------------- GroupNorm stats, stage 1: partial sums (atomic) ----------------
__global__ __launch_bounds__(256) void gn_partial_kernel(
    const float* __restrict__ x, float* __restrict__ partial) {
  const int bg = blockIdx.x >> 4, part = blockIdx.x & 15;
  const float4* base = (const float4*)(x + (size_t)bg * 2 * HWn) + part * 2048;
  float s = 0.f, s2 = 0.f;
  for (int i = threadIdx.x; i < 2048; i += 256) {
    const float4 v = base[i];
    s += v.x + v.y + v.z + v.w;
    s2 += v.x * v.x + v.y * v.y + v.z * v.z + v.w * v.w;
  }
  #pragma unroll
  for (int off = 32; off > 0; off >>= 1) {
    s  += __shfl_down(s, off, 64);
    s2 += __shfl_down(s2, off, 64);
  }
  __shared__ float red[8];
  const int wid = threadIdx.x >> 6, lid = threadIdx.x & 63;
  if (lid == 0) { red[wid * 2] = s; red[wid * 2 + 1] = s2; }
  __syncthreads();
  if (threadIdx.x == 0) {
    float ts = red[0] + red[2] + red[4] + red[6];
    float t2 = red[1] + red[3] + red[5] + red[7];
    atomicAdd(&partial[bg * 2], ts);
    atomicAdd(&partial[bg * 2 + 1], t2);
  }
}

// ---------------- GroupNorm stats, stage 2: finalize ----------------
__global__ void gn_final_kernel(const float* __restrict__ partial,
                                float* __restrict__ stats) {
  const int i = threadIdx.x;
  if (i < 128) {
    const float inv = 1.0f / (2.0f * HWn);
    const float mean = partial[2 * i] * inv;
    const float var = partial[2 * i + 1] * inv - mean * mean;
    stats[2 * i] = mean;
    stats[2 * i + 1] = rsqrtf(var + 1e-6f);
  }
}

// --------- Weight pre-pack: w1/w2 -> bf16 tables, vs9[9][64] shift table, pw0 ---------
__global__ void pack_weights_kernel(const float* __restrict__ w1,
                                    const float* __restrict__ w2,
                                    ushort* __restrict__ w1a, ushort* __restrict__ w1b,
                                    ushort* __restrict__ w2p,
                                    float* __restrict__ vs9, float* __restrict__ pw0) {
  const int t = threadIdx.x;  // 256 threads
  for (int i = t; i < 64 * 32; i += 256) {  // one bf16 pair per iter
    const int o = i >> 5, kp = (i & 31) * 2;
    *(unsigned*)&w1a[o * 64 + kp] = packbf(w1[o * 131 + kp], w1[o * 131 + kp + 1]);
    *(unsigned*)&w1b[o * 64 + kp] = packbf(w1[o * 131 + 64 + kp], w1[o * 131 + 64 + kp + 1]);
    *(unsigned*)&w2p[o * 64 + kp] = packbf(w2[o * 64 + kp], w2[o * 64 + kp + 1]);
  }
  if (t < 64) pw0[t] = w1[t * 131 + 128];
  // vs_s[k] = m0*pw0[k] + m1*pw1[k] + m2*pw2[k], s = isw*3+ish (isw,ish in 0..2)
  for (int i = t; i < 9 * 64; i += 256) {
    const int s = i >> 6, k = i & 63;
    const int isw = s / 3, ish = s % 3;
    const float m0 = kCA[isw] * kCI[ish];
    const float m1 = kCA[isw] * kSI[ish];
    const float m2 = kSA[isw];
    vs9[s * 64 + k] = m0 * w1[k * 131 + 128] + m1 * w1[k * 131 + 129] +
                      m2 * w1[k * 131 + 130];
  }
}

// ------- Dual GEMM (MFMA): Y = W_a @ relu(gn(x)), Z = W_b @ relu(gn(x)) + b1 -------
// x tile async-staged into LDS (XOR granule swizzle, 2-way-free reads)
// instead of 16 scalar strided global loads per lane.
// Output layout: NHWC bf16: Y[((b*64+w)*1024+h)*64 + k]
__global__ __launch_bounds__(256, 3) void dual_gemm_kernel(
    const float* __restrict__ x, const float* __restrict__ stats,
    const float* __restrict__ gw, const float* __restrict__ gb,
    const ushort* __restrict__ w1a, const ushort* __restrict__ w1b,
    const float* __restrict__ b1,
    ushort* __restrict__ Y, ushort* __restrict__ Z) {
  __shared__ float2 scsh[64];
  __shared__ float bias[64];
  __shared__ __align__(16) float xl[64 * 16 * 4];  // [c][slot][4f]; slot=g^(c&15)
  __shared__ __align__(16) ushort dsY[64 * 72];
  __shared__ __align__(16) ushort dsZ[64 * 72];
  const int blk = blockIdx.x;
  const int h0 = (blk & 15) * 64;
  const int w  = (blk >> 4) & 63;
  const int b  = blk >> 10;
  const int t  = threadIdx.x;
  const int lane = t & 63, wv = t >> 6;
  const int n = lane & 15, q = lane >> 4;

  // async stage x[c=0..63][h0..h0+63] (fp32, 64 rows x 16 granules of 16B)
  const float* xb = x + (size_t)b * CHWn + (size_t)w * Hn;
  #pragma unroll
  for (int p = 0; p < 4; p++) {
    const int slot = t + 256 * p;
    const int c = slot >> 4, g = slot & 15;
    const int G = g ^ (c & 15);
    gload16(&xb[(size_t)c * HWn + h0 + G * 4], &xl[(wv * 64 + 256 * p) * 4]);
  }

  if (t < 64) {
    const int g = t >> 1;
    const float mean = stats[(b * 32 + g) * 2];
    const float rstd = stats[(b * 32 + g) * 2 + 1];
    const float sc = rstd * gw[t];
    scsh[t] = make_float2(sc, gb[t] - mean * sc);
    bias[t] = b1[t];
  }
  __syncthreads();  // xl (vmcnt drained by barrier) + scsh visible

  // B fragments (xn) from LDS. n = local j col.
  const int jloc = wv * 16 + n;  // local h
  const int g0 = jloc >> 2, w0 = jloc & 3;
  Frag Bf[2];
  #pragma unroll
  for (int kh = 0; kh < 2; kh++) {
    unsigned d[4];
    #pragma unroll
    for (int p = 0; p < 4; p++) {
      const int c0 = kh * 32 + q * 8 + p * 2;
      const float2 s0 = scsh[c0], s1 = scsh[c0 + 1];
      const float xv0 = xl[(c0 * 16 + (g0 ^ (c0 & 15))) * 4 + w0];
      const float xv1 = xl[((c0 + 1) * 16 + (g0 ^ ((c0 + 1) & 15))) * 4 + w0];
      const float v0 = fmaxf(xv0 * s0.x + s0.y, 0.f);
      const float v1 = fmaxf(xv1 * s1.x + s1.y, 0.f);
      d[p] = packbf(v0, v1);
    }
    Bf[kh].u = make_uint4(d[0], d[1], d[2], d[3]);
  }

  f32x4 accY[4], accZ[4];
  #pragma unroll
  for (int os = 0; os < 4; os++) { accY[os] = (f32x4)0.f; accZ[os] = (f32x4)0.f; }

  #pragma unroll
  for (int os = 0; os < 4; os++) {
    const int o = os * 16 + n;  // A row m = lane&15
    #pragma unroll
    for (int kh = 0; kh < 2; kh++) {
      const int k = kh * 32 + q * 8;
      Frag fa, fb;
      fa.u = *(const uint4*)&w1a[o * 64 + k];  // pre-packed bf16, 16B aligned
      fb.u = *(const uint4*)&w1b[o * 64 + k];
      accY[os] = __builtin_amdgcn_mfma_f32_16x16x32_bf16(fa.s, Bf[kh].s, accY[os], 0, 0, 0);
      accZ[os] = __builtin_amdgcn_mfma_f32_16x16x32_bf16(fb.s, Bf[kh].s, accZ[os], 0, 0, 0);
    }
  }

  // D -> LDS repack: ds[j][o] (stride 72), bf16 pairs along o.
  const int jl = wv * 16 + n;
  #pragma unroll
  for (int os = 0; os < 4; os++) {
    #pragma unroll
    for (int rp = 0; rp < 4; rp += 2) {
      const int o = os * 16 + q * 4 + rp;
      *(unsigned*)&dsY[jl * 72 + o] = packbf(accY[os][rp], accY[os][rp + 1]);
      *(unsigned*)&dsZ[jl * 72 + o] =
          packbf(accZ[os][rp] + bias[o], accZ[os][rp + 1] + bias[o + 1]);
    }
  }
  __syncthreads();

  // Coalesced NHWC store
  #pragma unroll
  for (int p = 0; p < 2; p++) {
    const int slot = t + 256 * p;
    const int j = slot >> 3, og = slot & 7;
    const size_t gidx = (((size_t)b * Wn + w) * Hn + h0 + j) * 64 + og * 8;
    *(uint4*)&Y[gidx] = *(const uint4*)&dsY[j * 72 + og * 8];
    *(uint4*)&Z[gidx] = *(const uint4*)&dsZ[j * 72 + og * 8];
  }
}

// ---- 9-shift fused MFMA: out = max_s( W2 @ relu(Y_s + Z + pe_s) ) + b2 (+ x) ----
// All THREE Y w-columns staged up-front via async global_load_lds into a
// triple buffer (r4's max-MLP schedule, now register-free -> no spill), then
// ONE barrier and 9 straight-line shifts with zero further synchronization.
// w2 A-fragments stream from swizzled LDS (r8, 2-way-free).
__global__ __launch_bounds__(256, 3) void shift_max_kernel(
    const ushort* __restrict__ Y, const ushort* __restrict__ Z,
    const float* __restrict__ r, const float* __restrict__ vs9,
    const float* __restrict__ pw0, const ushort* __restrict__ w2p,
    const float* __restrict__ b2,
    const float* __restrict__ xres, const int add_res,
    float* __restrict__ out) {
  __shared__ __align__(16) ushort ys3[3][66 * 64];  // [wi][jj*64 + swz granule]
  __shared__ __align__(16) ushort w2l[64 * 64];     // [o][granule g at slot g^(o&7)]
  __shared__ float rsh[3][68];
  __shared__ __align__(16) float vsl[9 * 64];
  const int blk = blockIdx.x;
  const int h0 = (blk & 15) * 64;
  const int w  = (blk >> 4) & 63;
  const int b  = blk >> 10;
  const int t  = threadIdx.x;
  const int lane = t & 63, wv = t >> 6;
  const int n = lane & 15, q = lane >> 4;
  const int jl = wv * 16 + n;  // this lane's B column (local j)

  const ushort* Yb = Y + (size_t)b * (size_t)Wn * Hn * 64;

  // stage one Y w-column into ys3[wi] via async global->LDS (XOR-swizzled src)
  auto stage_col = [&](int wi, int wsrc) {
    const size_t ybase = (size_t)wsrc * (Hn * 64);
    #pragma unroll
    for (int p = 0; p < 3; p++) {
      const int slot = t + 256 * p;
      if (slot < 66 * 8) {
        const int jj = slot >> 3, S = slot & 7;
        const int G = S ^ (jj & 7);
        const int hsrc = (h0 + jj - 1 + 1024) & 1023;
        gload16(&Yb[ybase + (size_t)hsrc * 64 + G * 8],
                &ys3[wi][(wv * 64 + 256 * p) * 8]);
      }
    }
  };

  // issue ALL staging up front: wi holds wsrc = w + wi - 1 (compute uses 1-sw)
  stage_col(0, (w + 63) & 63);
  stage_col(1, w);
  stage_col(2, (w + 1) & 63);

  // w2 -> LDS, granule-swizzled: slot s = g ^ (o&7)
  #pragma unroll
  for (int i0 = 0; i0 < 2; i0++) {
    const int i = t + i0 * 256;
    const int o = i >> 3, g = i & 7;
    *(uint4*)&w2l[o * 64 + (g ^ (o & 7)) * 8] = *(const uint4*)&w2p[o * 64 + g * 8];
  }
  // vs table -> LDS (576 floats = 144 float4)
  if (t < 144) ((float4*)vsl)[t] = ((const float4*)vs9)[t];
  // r halo
  for (int i = t; i < 3 * 66; i += 256) {
    const int wi = i / 66, jj = i - wi * 66;
    const int wsrc = (w + wi - 1 + 64) & 63;
    const int hsrc = (h0 + jj - 1 + 1024) & 1023;
    rsh[wi][jj] = r[(size_t)b * HWn + wsrc * Hn + hsrc];
  }

  // z row (direct global, coalesced) folded with center-r term:
  // zc[k] = z[k] - rc*pw0[k]  (pw0 read transiently, not kept)
  const float rc = r[(size_t)b * HWn + (size_t)w * Hn + h0 + jl];
  float zcA[8], zcB[8];
  {
    const size_t zbase = (((size_t)b * Wn + w) * Hn + h0 + jl) * 64;
    const uint4 z0 = *(const uint4*)&Z[zbase + q * 8];
    const uint4 z1 = *(const uint4*)&Z[zbase + 32 + q * 8];
    const float4 pwA0 = *(const float4*)&pw0[q * 8];
    const float4 pwA1 = *(const float4*)&pw0[q * 8 + 4];
    const float4 pwB0 = *(const float4*)&pw0[32 + q * 8];
    const float4 pwB1 = *(const float4*)&pw0[32 + q * 8 + 4];
    const float pwA[8] = {pwA0.x, pwA0.y, pwA0.z, pwA0.w, pwA1.x, pwA1.y, pwA1.z, pwA1.w};
    const float pwB[8] = {pwB0.x, pwB0.y, pwB0.z, pwB0.w, pwB1.x, pwB1.y, pwB1.z, pwB1.w};
    const unsigned zw0[4] = {z0.x, z0.y, z0.z, z0.w};
    const unsigned zw1[4] = {z1.x, z1.y, z1.z, z1.w};
    #pragma unroll
    for (int p = 0; p < 4; p++) {
      zcA[2 * p]     = bflo(zw0[p]) - rc * pwA[2 * p];
      zcA[2 * p + 1] = bfhi(zw0[p]) - rc * pwA[2 * p + 1];
      zcB[2 * p]     = bflo(zw1[p]) - rc * pwB[2 * p];
      zcB[2 * p + 1] = bfhi(zw1[p]) - rc * pwB[2 * p + 1];
    }
  }

  __syncthreads();  // all LDS (incl. async ys3, vmcnt drained) visible

  f32x4 om[4];
  #pragma unroll
  for (int os = 0; os < 4; os++) om[os] = (f32x4)(-INFINITY);

  #pragma unroll
  for (int sw = -1; sw <= 1; sw++) {
    const int isw = sw + 1;
    const ushort* ysb = ys3[1 - sw];  // wsrc = w - sw
    #pragma unroll
    for (int sh = -1; sh <= 1; sh++) {
      const int ish = sh + 1;
      const float rsv = rsh[1 - sw][jl - sh + 1];
      const float* vrow = &vsl[(isw * 3 + ish) * 64];
      const int ro = jl - sh + 1;
      Frag Bf0, Bf1;
      // A-half (k 0..31) fully before B-half: halves transient pressure
      {
        const float4 vA0 = *(const float4*)&vrow[q * 8];
        const float4 vA1 = *(const float4*)&vrow[q * 8 + 4];
        const float vsA[8] = {vA0.x, vA0.y, vA0.z, vA0.w, vA1.x, vA1.y, vA1.z, vA1.w};
        const uint4 y0 = *(const uint4*)&ysb[ro * 64 + (q ^ (ro & 7)) * 8];
        const unsigned yw0[4] = {y0.x, y0.y, y0.z, y0.w};
        unsigned hw0[4];
        #pragma unroll
        for (int p = 0; p < 4; p++) {
          const float hA0 = fmaf(rsv, vsA[2 * p],     bflo(yw0[p]) + zcA[2 * p]);
          const float hA1 = fmaf(rsv, vsA[2 * p + 1], bfhi(yw0[p]) + zcA[2 * p + 1]);
          hw0[p] = packbf(fmaxf(hA0, 0.f), fmaxf(hA1, 0.f));
        }
        Bf0.u = make_uint4(hw0[0], hw0[1], hw0[2], hw0[3]);
      }
      {
        const float4 vB0 = *(const float4*)&vrow[32 + q * 8];
        const float4 vB1 = *(const float4*)&vrow[32 + q * 8 + 4];
        const float vsB[8] = {vB0.x, vB0.y, vB0.z, vB0.w, vB1.x, vB1.y, vB1.z, vB1.w};
        const uint4 y1 = *(const uint4*)&ysb[ro * 64 + ((q + 4) ^ (ro & 7)) * 8];
        const unsigned yw1[4] = {y1.x, y1.y, y1.z, y1.w};
        unsigned hw1[4];
        #pragma unroll
        for (int p = 0; p < 4; p++) {
          const float hB0 = fmaf(rsv, vsB[2 * p],     bflo(yw1[p]) + zcB[2 * p]);
          const float hB1 = fmaf(rsv, vsB[2 * p + 1], bfhi(yw1[p]) + zcB[2 * p + 1]);
          hw1[p] = packbf(fmaxf(hB0, 0.f), fmaxf(hB1, 0.f));
        }
        Bf1.u = make_uint4(hw1[0], hw1[1], hw1[2], hw1[3]);
      }
      // GEMM with A-fragments streamed from swizzled LDS
      #pragma unroll
      for (int os = 0; os < 4; os++) {
        const int orow = (os * 16 + n) * 64;
        Frag fa0, fa1;
        fa0.u = *(const uint4*)&w2l[orow + (q ^ (n & 7)) * 8];
        fa1.u = *(const uint4*)&w2l[orow + ((4 + q) ^ (n & 7)) * 8];
        f32x4 acc = (f32x4)0.f;
        acc = __builtin_amdgcn_mfma_f32_16x16x32_bf16(fa0.s, Bf0.s, acc, 0, 0, 0);
        acc = __builtin_amdgcn_mfma_f32_16x16x32_bf16(fa1.s, Bf1.s, acc, 0, 0, 0);
        #pragma unroll
        for (int e = 0; e < 4; e++) om[os][e] = fmaxf(om[os][e], acc[e]);
      }
    }
  }

  // epilogue: D layout col=lane&15 (j), row=q*4+e (o)
  const int jgl = h0 + jl;
  #pragma unroll
  for (int os = 0; os < 4; os++) {
    #pragma unroll
    for (int e = 0; e < 4; e++) {
      const int o = os * 16 + q * 4 + e;
      const size_t idx = ((size_t)b * Cn + o) * HWn + (size_t)w * Hn + jgl;
      float v = om[os][e] + b2[o];
      if (add_res) v += xres[idx];
      out[idx] = v;
    }
  }
}

}  // namespace

extern "C" void kernel_launch(void* const* d_in, const int* in_sizes, int n_in,
                              void* d_out, int out_size, void* d_ws, size_t ws_size,
                              hipStream_t stream) {
  const float* x    = (const float*)d_in[0];
  const float* r    = (const float*)d_in[1];
  const float* n1w  = (const float*)d_in[2];
  const float* n1b  = (const float*)d_in[3];
  const float* c1w1 = (const float*)d_in[4];
  const float* c1b1 = (const float*)d_in[5];
  const float* c1w2 = (const float*)d_in[6];
  const float* c1b2 = (const float*)d_in[7];
  const float* n2w  = (const float*)d_in[8];
  const float* n2b  = (const float*)d_in[9];
  const float* c2w1 = (const float*)d_in[10];
  const float* c2b1 = (const float*)d_in[11];
  const float* c2w2 = (const float*)d_in[12];
  const float* c2b2 = (const float*)d_in[13];
  float* out = (float*)d_out;

  // ws: [partial 256f][stats 256f][vs9 576f][pw0 64f][pad to 8192B]
  //     [Y bf16 32MiB][Z bf16 32MiB][w1a 8K][w1b 8K][w2p 8K]
  float* partial = (float*)d_ws;
  float* statsf  = partial + 256;
  float* vs9     = partial + 512;
  float* pw0     = partial + 1088;
  ushort* Ybf = (ushort*)((char*)d_ws + 8192);
  ushort* Zbf = Ybf + (size_t)Bn * Wn * Hn * 64;
  ushort* w1a = Zbf + (size_t)Bn * Wn * Hn * 64;
  ushort* w1b = w1a + 64 * 64;
  ushort* w2p = w1b + 64 * 64;

  // ---- block 1 ----
  hipMemsetAsync(partial, 0, 256 * sizeof(float), stream);
  gn_partial_kernel<<<2048, 256, 0, stream>>>(x, partial);
  gn_final_kernel<<<1, 128, 0, stream>>>(partial, statsf);
  pack_weights_kernel<<<1, 256, 0, stream>>>(c1w1, c1w2, w1a, w1b, w2p, vs9, pw0);
  dual_gemm_kernel<<<4096, 256, 0, stream>>>(x, statsf, n1w, n1b, w1a, w1b, c1b1, Ybf, Zbf);
  shift_max_kernel<<<4096, 256, 0, stream>>>(Ybf, Zbf, r, vs9, pw0, w2p, c1b2, x, 0, out);
  // ---- block 2 (edge_conv1 result parked in d_out) ----
  hipMemsetAsync(partial, 0, 256 * sizeof(float), stream);
  gn_partial_kernel<<<2048, 256, 0, stream>>>(out, partial);
  gn_final_kernel<<<1, 128, 0, stream>>>(partial, statsf);
  pack_weights_kernel<<<1, 256, 0, stream>>>(c2w1, c2w2, w1a, w1b, w2p, vs9, pw0);
  dual_gemm_kernel<<<4096, 256, 0, stream>>>(out, statsf, n2w, n2b, w1a, w1b, c2b1, Ybf, Zbf);
  shift_max_kernel<<<4096, 256, 0, stream>>>(Ybf, Zbf, r, vs9, pw0, w2p, c2b2, x, 1, out);
}

// Round 10
// 354.697 us; speedup vs baseline: 1.2194x; 1.2194x over previous
//
#include <hip/hip_runtime.h>
#include <hip/hip_bf16.h>
#include <cmath>
#include <math.h>

namespace {

constexpr int Bn = 4;
constexpr int Cn = 64;
constexpr int Wn = 64;
constexpr int Hn = 1024;
constexpr int HWn = Wn * Hn;      // 65536
constexpr int CHWn = Cn * HWn;    // 4194304

typedef float f32x4 __attribute__((ext_vector_type(4)));
typedef short bf16x8 __attribute__((ext_vector_type(8)));
union Frag { uint4 u; bf16x8 s; };

// Compile-time shift trig (index 0..2 = shift -1..+1).
constexpr float kCA[3] = {0.9999811753f, 1.0f, 0.9999811753f};   // cos(sw*AZI)
constexpr float kSA[3] = {-0.0061358846f, 0.0f, 0.0061358846f};  // sin(sw*AZI)
constexpr float kCI[3] = {0.9999658257f, 1.0f, 0.9999658257f};   // cos(sh*INC)
constexpr float kSI[3] = {-0.0082672549f, 0.0f, 0.0082672549f};  // sin(sh*INC)

// RNE pack of two f32 -> packed bf16x2 (compiler emits v_cvt_pk_bf16_f32).
__device__ inline unsigned packbf(float a, float b) {
  union { __hip_bfloat162 h; unsigned u; } c;
  c.h = __float22bfloat162_rn(make_float2(a, b));
  return c.u;
}
__device__ inline float bflo(unsigned d) { return __uint_as_float(d << 16); }
__device__ inline float bfhi(unsigned d) { return __uint_as_float(d & 0xFFFF0000u); }

// Async global->LDS, 16B per lane. lptr must be wave-uniform; HW writes
// lptr + lane*16 for each active lane.
__device__ inline void gload16(const void* g, void* l) {
  __builtin_amdgcn_global_load_lds(
      (const __attribute__((address_space(1))) void*)g,
      (__attribute__((address_space(3))) void*)l, 16, 0, 0);
}

// ---------------- GroupNorm stats, stage 1: partial sums (atomic) ----------------
__global__ __launch_bounds__(256) void gn_partial_kernel(
    const float* __restrict__ x, float* __restrict__ partial) {
  const int bg = blockIdx.x >> 4, part = blockIdx.x & 15;
  const float4* base = (const float4*)(x + (size_t)bg * 2 * HWn) + part * 2048;
  float s = 0.f, s2 = 0.f;
  for (int i = threadIdx.x; i < 2048; i += 256) {
    const float4 v = base[i];
    s += v.x + v.y + v.z + v.w;
    s2 += v.x * v.x + v.y * v.y + v.z * v.z + v.w * v.w;
  }
  #pragma unroll
  for (int off = 32; off > 0; off >>= 1) {
    s  += __shfl_down(s, off, 64);
    s2 += __shfl_down(s2, off, 64);
  }
  __shared__ float red[8];
  const int wid = threadIdx.x >> 6, lid = threadIdx.x & 63;
  if (lid == 0) { red[wid * 2] = s; red[wid * 2 + 1] = s2; }
  __syncthreads();
  if (threadIdx.x == 0) {
    float ts = red[0] + red[2] + red[4] + red[6];
    float t2 = red[1] + red[3] + red[5] + red[7];
    atomicAdd(&partial[bg * 2], ts);
    atomicAdd(&partial[bg * 2 + 1], t2);
  }
}

// ---------------- GroupNorm stats, stage 2: finalize ----------------
__global__ void gn_final_kernel(const float* __restrict__ partial,
                                float* __restrict__ stats) {
  const int i = threadIdx.x;
  if (i < 128) {
    const float inv = 1.0f / (2.0f * HWn);
    const float mean = partial[2 * i] * inv;
    const float var = partial[2 * i + 1] * inv - mean * mean;
    stats[2 * i] = mean;
    stats[2 * i + 1] = rsqrtf(var + 1e-6f);
  }
}

// --------- Weight pre-pack: w1/w2 -> bf16 tables, vs9[9][64] shift table, pw0 ---------
__global__ void pack_weights_kernel(const float* __restrict__ w1,
                                    const float* __restrict__ w2,
                                    ushort* __restrict__ w1a, ushort* __restrict__ w1b,
                                    ushort* __restrict__ w2p,
                                    float* __restrict__ vs9, float* __restrict__ pw0) {
  const int t = threadIdx.x;  // 256 threads
  for (int i = t; i < 64 * 32; i += 256) {  // one bf16 pair per iter
    const int o = i >> 5, kp = (i & 31) * 2;
    *(unsigned*)&w1a[o * 64 + kp] = packbf(w1[o * 131 + kp], w1[o * 131 + kp + 1]);
    *(unsigned*)&w1b[o * 64 + kp] = packbf(w1[o * 131 + 64 + kp], w1[o * 131 + 64 + kp + 1]);
    *(unsigned*)&w2p[o * 64 + kp] = packbf(w2[o * 64 + kp], w2[o * 64 + kp + 1]);
  }
  if (t < 64) pw0[t] = w1[t * 131 + 128];
  // vs_s[k] = m0*pw0[k] + m1*pw1[k] + m2*pw2[k], s = isw*3+ish (isw,ish in 0..2)
  for (int i = t; i < 9 * 64; i += 256) {
    const int s = i >> 6, k = i & 63;
    const int isw = s / 3, ish = s % 3;
    const float m0 = kCA[isw] * kCI[ish];
    const float m1 = kCA[isw] * kSI[ish];
    const float m2 = kSA[isw];
    vs9[s * 64 + k] = m0 * w1[k * 131 + 128] + m1 * w1[k * 131 + 129] +
                      m2 * w1[k * 131 + 130];
  }
}

// ------- Dual GEMM (MFMA): Y = W_a @ relu(gn(x)), Z = W_b @ relu(gn(x)) + b1 -------
// (r8 version — direct scalar x loads; the r9 LDS-staging variant regressed.)
// Output layout: NHWC bf16: Y[((b*64+w)*1024+h)*64 + k]
__global__ __launch_bounds__(256, 3) void dual_gemm_kernel(
    const float* __restrict__ x, const float* __restrict__ stats,
    const float* __restrict__ gw, const float* __restrict__ gb,
    const ushort* __restrict__ w1a, const ushort* __restrict__ w1b,
    const float* __restrict__ b1,
    ushort* __restrict__ Y, ushort* __restrict__ Z) {
  __shared__ float2 scsh[64];
  __shared__ float bias[64];
  __shared__ __align__(16) ushort dsY[64 * 72];
  __shared__ __align__(16) ushort dsZ[64 * 72];
  const int blk = blockIdx.x;
  const int h0 = (blk & 15) * 64;
  const int w  = (blk >> 4) & 63;
  const int b  = blk >> 10;
  const int t  = threadIdx.x;
  const int lane = t & 63, wv = t >> 6;
  const int n = lane & 15, q = lane >> 4;

  if (t < 64) {
    const int g = t >> 1;
    const float mean = stats[(b * 32 + g) * 2];
    const float rstd = stats[(b * 32 + g) * 2 + 1];
    const float sc = rstd * gw[t];
    scsh[t] = make_float2(sc, gb[t] - mean * sc);
    bias[t] = b1[t];
  }
  __syncthreads();

  // B fragments (xn), built directly in registers. n = local j col.
  const int jg = h0 + wv * 16 + n;  // global h
  const float* xb = x + (size_t)b * CHWn + (size_t)w * Hn;
  Frag Bf[2];
  #pragma unroll
  for (int kh = 0; kh < 2; kh++) {
    unsigned d[4];
    #pragma unroll
    for (int p = 0; p < 4; p++) {
      const int c0 = kh * 32 + q * 8 + p * 2;
      const float2 s0 = scsh[c0], s1 = scsh[c0 + 1];
      const float v0 = fmaxf(xb[(size_t)c0 * HWn + jg] * s0.x + s0.y, 0.f);
      const float v1 = fmaxf(xb[(size_t)(c0 + 1) * HWn + jg] * s1.x + s1.y, 0.f);
      d[p] = packbf(v0, v1);
    }
    Bf[kh].u = make_uint4(d[0], d[1], d[2], d[3]);
  }

  f32x4 accY[4], accZ[4];
  #pragma unroll
  for (int os = 0; os < 4; os++) { accY[os] = (f32x4)0.f; accZ[os] = (f32x4)0.f; }

  #pragma unroll
  for (int os = 0; os < 4; os++) {
    const int o = os * 16 + n;  // A row m = lane&15
    #pragma unroll
    for (int kh = 0; kh < 2; kh++) {
      const int k = kh * 32 + q * 8;
      Frag fa, fb;
      fa.u = *(const uint4*)&w1a[o * 64 + k];  // pre-packed bf16, 16B aligned
      fb.u = *(const uint4*)&w1b[o * 64 + k];
      accY[os] = __builtin_amdgcn_mfma_f32_16x16x32_bf16(fa.s, Bf[kh].s, accY[os], 0, 0, 0);
      accZ[os] = __builtin_amdgcn_mfma_f32_16x16x32_bf16(fb.s, Bf[kh].s, accZ[os], 0, 0, 0);
    }
  }

  // D -> LDS repack: ds[j][o] (stride 72), bf16 pairs along o.
  const int jl = wv * 16 + n;
  #pragma unroll
  for (int os = 0; os < 4; os++) {
    #pragma unroll
    for (int rp = 0; rp < 4; rp += 2) {
      const int o = os * 16 + q * 4 + rp;
      *(unsigned*)&dsY[jl * 72 + o] = packbf(accY[os][rp], accY[os][rp + 1]);
      *(unsigned*)&dsZ[jl * 72 + o] =
          packbf(accZ[os][rp] + bias[o], accZ[os][rp + 1] + bias[o + 1]);
    }
  }
  __syncthreads();

  // Coalesced NHWC store
  #pragma unroll
  for (int p = 0; p < 2; p++) {
    const int slot = t + 256 * p;
    const int j = slot >> 3, og = slot & 7;
    const size_t gidx = (((size_t)b * Wn + w) * Hn + h0 + j) * 64 + og * 8;
    *(uint4*)&Y[gidx] = *(const uint4*)&dsY[j * 72 + og * 8];
    *(uint4*)&Z[gidx] = *(const uint4*)&dsZ[j * 72 + og * 8];
  }
}

// ---- 9-shift fused MFMA: out = max_s( W2 @ relu(Y_s + Z + pe_s) ) + b2 (+ x) ----
// r8 body with the 3 Y-columns staged up-front (triple buffer, 9 wave-DMAs in
// flight) and ONE barrier. The sw loop is pinned with #pragma unroll 1 so the
// scheduler cannot hoist ds_reads across shifts (that hoisting is what spilled
// r9's fully-unrolled version). Register pressure therefore stays at r8's ~76.
__global__ __launch_bounds__(256, 3) void shift_max_kernel(
    const ushort* __restrict__ Y, const ushort* __restrict__ Z,
    const float* __restrict__ r, const float* __restrict__ vs9,
    const float* __restrict__ pw0, const ushort* __restrict__ w2p,
    const float* __restrict__ b2,
    const float* __restrict__ xres, const int add_res,
    float* __restrict__ out) {
  __shared__ __align__(16) ushort ys3[3][66 * 64];  // [wi][jj*64 + swz granule]
  __shared__ __align__(16) ushort w2l[64 * 64];     // [o][granule g at slot g^(o&7)]
  __shared__ float rsh[3][68];
  __shared__ __align__(16) float vsl[9 * 64];
  const int blk = blockIdx.x;
  const int h0 = (blk & 15) * 64;
  const int w  = (blk >> 4) & 63;
  const int b  = blk >> 10;
  const int t  = threadIdx.x;
  const int lane = t & 63, wv = t >> 6;
  const int n = lane & 15, q = lane >> 4;
  const int jl = wv * 16 + n;  // this lane's B column (local j)

  const ushort* Yb = Y + (size_t)b * (size_t)Wn * Hn * 64;

  // stage one Y w-column into ys3[wi] via async global->LDS (XOR-swizzled src)
  auto stage_col = [&](int wi, int wsrc) {
    const size_t ybase = (size_t)wsrc * (Hn * 64);
    #pragma unroll
    for (int p = 0; p < 3; p++) {
      const int slot = t + 256 * p;
      if (slot < 66 * 8) {
        const int jj = slot >> 3, S = slot & 7;
        const int G = S ^ (jj & 7);
        const int hsrc = (h0 + jj - 1 + 1024) & 1023;
        gload16(&Yb[ybase + (size_t)hsrc * 64 + G * 8],
                &ys3[wi][(wv * 64 + 256 * p) * 8]);
      }
    }
  };

  // issue ALL staging up front: wi holds wsrc = w + wi - 1 (compute uses 1-sw)
  stage_col(0, (w + 63) & 63);
  stage_col(1, w);
  stage_col(2, (w + 1) & 63);

  // w2 -> LDS, granule-swizzled: slot s = g ^ (o&7)
  #pragma unroll
  for (int i0 = 0; i0 < 2; i0++) {
    const int i = t + i0 * 256;
    const int o = i >> 3, g = i & 7;
    *(uint4*)&w2l[o * 64 + (g ^ (o & 7)) * 8] = *(const uint4*)&w2p[o * 64 + g * 8];
  }
  // vs table -> LDS (576 floats = 144 float4)
  if (t < 144) ((float4*)vsl)[t] = ((const float4*)vs9)[t];
  // r halo
  for (int i = t; i < 3 * 66; i += 256) {
    const int wi = i / 66, jj = i - wi * 66;
    const int wsrc = (w + wi - 1 + 64) & 63;
    const int hsrc = (h0 + jj - 1 + 1024) & 1023;
    rsh[wi][jj] = r[(size_t)b * HWn + wsrc * Hn + hsrc];
  }

  // z row (direct global, coalesced) folded with center-r term:
  // zc[k] = z[k] - rc*pw0[k]  (pw0 read transiently, not kept)
  const float rc = r[(size_t)b * HWn + (size_t)w * Hn + h0 + jl];
  float zcA[8], zcB[8];
  {
    const size_t zbase = (((size_t)b * Wn + w) * Hn + h0 + jl) * 64;
    const uint4 z0 = *(const uint4*)&Z[zbase + q * 8];
    const uint4 z1 = *(const uint4*)&Z[zbase + 32 + q * 8];
    const float4 pwA0 = *(const float4*)&pw0[q * 8];
    const float4 pwA1 = *(const float4*)&pw0[q * 8 + 4];
    const float4 pwB0 = *(const float4*)&pw0[32 + q * 8];
    const float4 pwB1 = *(const float4*)&pw0[32 + q * 8 + 4];
    const float pwA[8] = {pwA0.x, pwA0.y, pwA0.z, pwA0.w, pwA1.x, pwA1.y, pwA1.z, pwA1.w};
    const float pwB[8] = {pwB0.x, pwB0.y, pwB0.z, pwB0.w, pwB1.x, pwB1.y, pwB1.z, pwB1.w};
    const unsigned zw0[4] = {z0.x, z0.y, z0.z, z0.w};
    const unsigned zw1[4] = {z1.x, z1.y, z1.z, z1.w};
    #pragma unroll
    for (int p = 0; p < 4; p++) {
      zcA[2 * p]     = bflo(zw0[p]) - rc * pwA[2 * p];
      zcA[2 * p + 1] = bfhi(zw0[p]) - rc * pwA[2 * p + 1];
      zcB[2 * p]     = bflo(zw1[p]) - rc * pwB[2 * p];
      zcB[2 * p + 1] = bfhi(zw1[p]) - rc * pwB[2 * p + 1];
    }
  }

  __syncthreads();  // all LDS (incl. async ys3, vmcnt drained) visible

  f32x4 om[4];
  #pragma unroll
  for (int os = 0; os < 4; os++) om[os] = (f32x4)(-INFINITY);

  #pragma unroll 1  // real loop: stops cross-shift hoisting (r9's spill source)
  for (int sw = -1; sw <= 1; sw++) {
    const int isw = sw + 1;
    const ushort* ysb = &ys3[1 - sw][0];  // wsrc = w - sw
    #pragma unroll
    for (int sh = -1; sh <= 1; sh++) {
      const int ish = sh + 1;
      const float rsv = rsh[1 - sw][jl - sh + 1];
      const float* vrow = &vsl[(isw * 3 + ish) * 64];
      const int ro = jl - sh + 1;
      Frag Bf0, Bf1;
      // A-half (k 0..31) fully before B-half: halves transient pressure
      {
        const float4 vA0 = *(const float4*)&vrow[q * 8];
        const float4 vA1 = *(const float4*)&vrow[q * 8 + 4];
        const float vsA[8] = {vA0.x, vA0.y, vA0.z, vA0.w, vA1.x, vA1.y, vA1.z, vA1.w};
        const uint4 y0 = *(const uint4*)&ysb[ro * 64 + (q ^ (ro & 7)) * 8];
        const unsigned yw0[4] = {y0.x, y0.y, y0.z, y0.w};
        unsigned hw0[4];
        #pragma unroll
        for (int p = 0; p < 4; p++) {
          const float hA0 = fmaf(rsv, vsA[2 * p],     bflo(yw0[p]) + zcA[2 * p]);
          const float hA1 = fmaf(rsv, vsA[2 * p + 1], bfhi(yw0[p]) + zcA[2 * p + 1]);
          hw0[p] = packbf(fmaxf(hA0, 0.f), fmaxf(hA1, 0.f));
        }
        Bf0.u = make_uint4(hw0[0], hw0[1], hw0[2], hw0[3]);
      }
      {
        const float4 vB0 = *(const float4*)&vrow[32 + q * 8];
        const float4 vB1 = *(const float4*)&vrow[32 + q * 8 + 4];
        const float vsB[8] = {vB0.x, vB0.y, vB0.z, vB0.w, vB1.x, vB1.y, vB1.z, vB1.w};
        const uint4 y1 = *(const uint4*)&ysb[ro * 64 + ((q + 4) ^ (ro & 7)) * 8];
        const unsigned yw1[4] = {y1.x, y1.y, y1.z, y1.w};
        unsigned hw1[4];
        #pragma unroll
        for (int p = 0; p < 4; p++) {
          const float hB0 = fmaf(rsv, vsB[2 * p],     bflo(yw1[p]) + zcB[2 * p]);
          const float hB1 = fmaf(rsv, vsB[2 * p + 1], bfhi(yw1[p]) + zcB[2 * p + 1]);
          hw1[p] = packbf(fmaxf(hB0, 0.f), fmaxf(hB1, 0.f));
        }
        Bf1.u = make_uint4(hw1[0], hw1[1], hw1[2], hw1[3]);
      }
      // GEMM with A-fragments streamed from swizzled LDS
      #pragma unroll
      for (int os = 0; os < 4; os++) {
        const int orow = (os * 16 + n) * 64;
        Frag fa0, fa1;
        fa0.u = *(const uint4*)&w2l[orow + (q ^ (n & 7)) * 8];
        fa1.u = *(const uint4*)&w2l[orow + ((4 + q) ^ (n & 7)) * 8];
        f32x4 acc = (f32x4)0.f;
        acc = __builtin_amdgcn_mfma_f32_16x16x32_bf16(fa0.s, Bf0.s, acc, 0, 0, 0);
        acc = __builtin_amdgcn_mfma_f32_16x16x32_bf16(fa1.s, Bf1.s, acc, 0, 0, 0);
        #pragma unroll
        for (int e = 0; e < 4; e++) om[os][e] = fmaxf(om[os][e], acc[e]);
      }
    }
  }

  // epilogue: D layout col=lane&15 (j), row=q*4+e (o)
  const int jgl = h0 + jl;
  #pragma unroll
  for (int os = 0; os < 4; os++) {
    #pragma unroll
    for (int e = 0; e < 4; e++) {
      const int o = os * 16 + q * 4 + e;
      const size_t idx = ((size_t)b * Cn + o) * HWn + (size_t)w * Hn + jgl;
      float v = om[os][e] + b2[o];
      if (add_res) v += xres[idx];
      out[idx] = v;
    }
  }
}

}  // namespace

extern "C" void kernel_launch(void* const* d_in, const int* in_sizes, int n_in,
                              void* d_out, int out_size, void* d_ws, size_t ws_size,
                              hipStream_t stream) {
  const float* x    = (const float*)d_in[0];
  const float* r    = (const float*)d_in[1];
  const float* n1w  = (const float*)d_in[2];
  const float* n1b  = (const float*)d_in[3];
  const float* c1w1 = (const float*)d_in[4];
  const float* c1b1 = (const float*)d_in[5];
  const float* c1w2 = (const float*)d_in[6];
  const float* c1b2 = (const float*)d_in[7];
  const float* n2w  = (const float*)d_in[8];
  const float* n2b  = (const float*)d_in[9];
  const float* c2w1 = (const float*)d_in[10];
  const float* c2b1 = (const float*)d_in[11];
  const float* c2w2 = (const float*)d_in[12];
  const float* c2b2 = (const float*)d_in[13];
  float* out = (float*)d_out;

  // ws: [partial 256f][stats 256f][vs9 576f][pw0 64f][pad to 8192B]
  //     [Y bf16 32MiB][Z bf16 32MiB][w1a 8K][w1b 8K][w2p 8K]
  float* partial = (float*)d_ws;
  float* statsf  = partial + 256;
  float* vs9     = partial + 512;
  float* pw0     = partial + 1088;
  ushort* Ybf = (ushort*)((char*)d_ws + 8192);
  ushort* Zbf = Ybf + (size_t)Bn * Wn * Hn * 64;
  ushort* w1a = Zbf + (size_t)Bn * Wn * Hn * 64;
  ushort* w1b = w1a + 64 * 64;
  ushort* w2p = w1b + 64 * 64;

  // ---- block 1 ----
  hipMemsetAsync(partial, 0, 256 * sizeof(float), stream);
  gn_partial_kernel<<<2048, 256, 0, stream>>>(x, partial);
  gn_final_kernel<<<1, 128, 0, stream>>>(partial, statsf);
  pack_weights_kernel<<<1, 256, 0, stream>>>(c1w1, c1w2, w1a, w1b, w2p, vs9, pw0);
  dual_gemm_kernel<<<4096, 256, 0, stream>>>(x, statsf, n1w, n1b, w1a, w1b, c1b1, Ybf, Zbf);
  shift_max_kernel<<<4096, 256, 0, stream>>>(Ybf, Zbf, r, vs9, pw0, w2p, c1b2, x, 0, out);
  // ---- block 2 (edge_conv1 result parked in d_out) ----
  hipMemsetAsync(partial, 0, 256 * sizeof(float), stream);
  gn_partial_kernel<<<2048, 256, 0, stream>>>(out, partial);
  gn_final_kernel<<<1, 128, 0, stream>>>(partial, statsf);
  pack_weights_kernel<<<1, 256, 0, stream>>>(c2w1, c2w2, w1a, w1b, w2p, vs9, pw0);
  dual_gemm_kernel<<<4096, 256, 0, stream>>>(out, statsf, n2w, n2b, w1a, w1b, c2b1, Ybf, Zbf);
  shift_max_kernel<<<4096, 256, 0, stream>>>(Ybf, Zbf, r, vs9, pw0, w2p, c2b2, x, 1, out);
}